// Round 4
// baseline (145.564 us; speedup 1.0000x reference)
//
#include <hip/hip_runtime.h>

#define BLOCK 256

static __device__ __forceinline__ float ldz(const float* __restrict__ p, int i, int n) {
    return (i >= 0 && i < n) ? p[i] : 0.f;
}

// Intra-wave LDS visibility: drain lgkmcnt, no s_barrier. Memory clobber stops
// the compiler reordering DS ops across it. (Waves never sync with each other.)
#define WAVE_SYNC() asm volatile("s_waitcnt lgkmcnt(0)" ::: "memory")

// Quad-filter taps, reversed/deinterleaved, sqrt2 folded into the highpass set.
struct QFilt {
    float b0e[5], b0o[5], a0e[5], a0o[5];
    float b1e[5], b1o[5], a1e[5], a1o[5];
};

static __device__ __forceinline__ QFilt load_qfilt(
    const float* __restrict__ g0a, const float* __restrict__ g0b,
    const float* __restrict__ g1a, const float* __restrict__ g1b) {
    const float S2 = 1.4142135623730951f;
    QFilt f;
#pragma unroll
    for (int i = 0; i < 5; ++i) {
        f.b0e[i] = g0b[8 - 2 * i]; f.b0o[i] = g0b[9 - 2 * i];
        f.a0e[i] = g0a[8 - 2 * i]; f.a0o[i] = g0a[9 - 2 * i];
        f.b1e[i] = S2 * g1b[8 - 2 * i]; f.b1o[i] = S2 * g1b[9 - 2 * i];
        f.a1e[i] = S2 * g1a[8 - 2 * i]; f.a1o[i] = S2 * g1a[9 - 2 * i];
    }
    return f;
}

// Quad out[4s..4s+3]. All inputs relative to ONE LDS base pointer so the
// backend can merge: lo as float2 (ds_read_b64 / ds_read2_b64), r/i pair at
// constant dword distance ioff (ds_read2_b32).
static __device__ __forceinline__ float4 quad_w(
    const float* base, int loOff, int riOff, int ioff, const QFilt& f) {
    float y0 = 0.f, y1 = 0.f, y2 = 0.f, y3 = 0.f;
#pragma unroll
    for (int i = 0; i < 5; ++i) {
        float2 lo2 = *reinterpret_cast<const float2*>(base + loOff + 2 * i);
        float ve = lo2.x, vo = lo2.y;
        float vr = base[riOff + i], vi = base[riOff + ioff + i];
        y0 = fmaf(ve, f.b0e[i], y0); y2 = fmaf(ve, f.b0o[i], y2);
        y1 = fmaf(vo, f.a0e[i], y1); y3 = fmaf(vo, f.a0o[i], y3);
        y0 = fmaf(vr, f.b1e[i], y0); y2 = fmaf(vr, f.b1o[i], y2);
        y1 = fmaf(vi, f.a1e[i], y1); y3 = fmaf(vi, f.a1o[i], y3);
    }
    return make_float4(y0, y1, y2, y3);
}

// Interleaved-window quad (pair_lvl only, unchanged semantics).
static __device__ __forceinline__ float4 quad_i(
    const float* __restrict__ lo_s, int lobase,
    const float* __restrict__ r_s, const float* __restrict__ i_s, int ribase,
    const QFilt& f) {
    float y0 = 0.f, y1 = 0.f, y2 = 0.f, y3 = 0.f;
#pragma unroll
    for (int i = 0; i < 5; ++i) {
        float ve = lo_s[lobase + 2 * i], vo = lo_s[lobase + 2 * i + 1];
        float vr = r_s[ribase + i], vi = i_s[ribase + i];
        y0 = fmaf(ve, f.b0e[i], y0); y2 = fmaf(ve, f.b0o[i], y2);
        y1 = fmaf(vo, f.a0e[i], y1); y3 = fmaf(vo, f.a0o[i], y3);
        y0 = fmaf(vr, f.b1e[i], y0); y2 = fmaf(vr, f.b1o[i], y2);
        y1 = fmaf(vi, f.a1e[i], y1); y3 = fmaf(vi, f.a1o[i], y3);
    }
    return make_float4(y0, y1, y2, y3);
}

static __device__ __forceinline__ float4 quad_d(
    const float* __restrict__ Ae, const float* __restrict__ Ao, int base,
    const float* __restrict__ r_s, const float* __restrict__ i_s, int ribase,
    const QFilt& f) {
    float y0 = 0.f, y1 = 0.f, y2 = 0.f, y3 = 0.f;
#pragma unroll
    for (int i = 0; i < 5; ++i) {
        float ve = Ae[base + i], vo = Ao[base + i];
        float vr = r_s[ribase + i], vi = i_s[ribase + i];
        y0 = fmaf(ve, f.b0e[i], y0); y2 = fmaf(ve, f.b0o[i], y2);
        y1 = fmaf(vo, f.a0e[i], y1); y3 = fmaf(vo, f.a0o[i], y3);
        y0 = fmaf(vr, f.b1e[i], y0); y2 = fmaf(vr, f.b1o[i], y2);
        y1 = fmaf(vi, f.a1e[i], y1); y3 = fmaf(vi, f.a1o[i], y3);
    }
    return make_float4(y0, y1, y2, y3);
}

// TWO fused coarse levels (R11 structure, unchanged — measured near floor).
__global__ void __launch_bounds__(BLOCK) pair_lvl(
    const float* __restrict__ up,
    const float* __restrict__ ru, const float* __restrict__ iu,
    const float* __restrict__ rl, const float* __restrict__ il,
    float* __restrict__ out,
    const float* __restrict__ g0a, const float* __restrict__ g0b,
    const float* __restrict__ g1a, const float* __restrict__ g1b,
    int L)
{
    __shared__ __align__(16) float upw[272], ruw[140], iuw[140], rlw[264], ilw[264];
    __shared__ __align__(16) float Ae[260], Ao[260];
    int tid = threadIdx.x, bx = blockIdx.x, row = blockIdx.y;
    int lup = L >> 2, lu8 = L >> 3, lql = L >> 2;
    const float* uprow = up + (size_t)row * lup;
    const float* rurow = ru + (size_t)row * lu8;
    const float* iurow = iu + (size_t)row * lu8;
    const float* rlrow = rl + (size_t)row * lql;
    const float* ilrow = il + (size_t)row * lql;
    bool bnd = (bx == 0) || (bx == (int)gridDim.x - 1);
    int S = bx << 8;
    int sAu = (S >> 1) - 1;
    int gu = S - 8;
    int gru = (S >> 1) - 4;
    int grl = S - 4;

    for (int i = tid; i < 270; i += BLOCK) {
        const float* src; float* dst; int k, gb, len;
        if (i < 68)       { src = uprow; dst = upw; k = i;       gb = gu + 4 * k;  len = lup; }
        else if (i < 103) { src = rurow; dst = ruw; k = i - 68;  gb = gru + 4 * k; len = lu8; }
        else if (i < 138) { src = iurow; dst = iuw; k = i - 103; gb = gru + 4 * k; len = lu8; }
        else if (i < 204) { src = rlrow; dst = rlw; k = i - 138; gb = grl + 4 * k; len = lql; }
        else              { src = ilrow; dst = ilw; k = i - 204; gb = grl + 4 * k; len = lql; }
        float4 v;
        if (!bnd) v = *reinterpret_cast<const float4*>(src + gb);
        else { v.x = ldz(src, gb, len); v.y = ldz(src, gb + 1, len);
               v.z = ldz(src, gb + 2, len); v.w = ldz(src, gb + 3, len); }
        *reinterpret_cast<float4*>(dst + 4 * k) = v;
    }
    __syncthreads();

    QFilt f = load_qfilt(g0a, g0b, g1a, g1b);
    if (tid < 130) {
        float4 q = quad_i(upw, 2 * tid + 2, ruw, iuw, tid + 1, f);
        if (bnd) {
            int sp = sAu + tid;
            if (sp < 0 || sp >= lu8) q = make_float4(0.f, 0.f, 0.f, 0.f);
        }
        Ae[2 * tid] = q.x; Ae[2 * tid + 1] = q.z;
        Ao[2 * tid] = q.y; Ao[2 * tid + 1] = q.w;
    }
    __syncthreads();

    float4 res = quad_d(Ae, Ao, tid, rlw, ilw, tid + 2, f);
    reinterpret_cast<float4*>(out + (size_t)row * L)[S + tid] = res;
}

// R16: wave-autonomous 4-level final. Each WAVE owns a 256-output sub-tile and
// runs stage -> x3 -> x2 -> x1 -> epilogue privately in its own LDS region.
// NO __syncthreads anywhere: intra-wave LDS visibility needs only
// s_waitcnt lgkmcnt(0). Stalls decorrelate across ~32 independent waves/CU.
// LDS-pipe load cut via float2 lo reads + single-array r/i (ds_read2 merge).
// Per-wave LDS map (dword offsets within the wave's WSTR region):
#define O_X4 0      // x4 window  [48]
#define O_R3 48     // yh3 r [24], i at +24
#define O_I3 72
#define O_R2 96     // yh2 r [40], i at +40
#define O_I2 136
#define O_R1 176    // yh1 r [72], i at +72
#define O_I1 248
#define O_X3 320    // x3 values [80]
#define O_X2 400    // x2 values [144]
#define O_X1 544    // x1 quads  [264]
#define WSTR 816    // per-wave stride (16B-aligned: 816*4 = 3264)

__global__ void __launch_bounds__(BLOCK) final4_wave(
    const float* __restrict__ x4,                                 // T/8 per row
    const float* __restrict__ r3, const float* __restrict__ i3,   // T/16 per row
    const float* __restrict__ r2, const float* __restrict__ i2,   // T/8 per row
    const float* __restrict__ r1, const float* __restrict__ i1,   // T/4 per row
    const float* __restrict__ r0, const float* __restrict__ i0,   // T/2 per row
    float* __restrict__ out,                                      // T per row
    const float* __restrict__ g0a, const float* __restrict__ g0b,
    const float* __restrict__ g1a, const float* __restrict__ g1b,
    const float* __restrict__ g0o, const float* __restrict__ g1o,
    int T_)
{
    const float S2 = 1.4142135623730951f;
    __shared__ __align__(16) float S[4 * WSTR];   // 13056 B

    int tid = threadIdx.x;
    int lane = tid & 63, wv = tid >> 6;
    int row = blockIdx.y;
    int t2 = T_ >> 1, t4 = T_ >> 2, t8 = T_ >> 3, t16 = T_ >> 4;
    int NT256 = T_ >> 8;                          // wave-tiles per row
    int widx = blockIdx.x * 4 + wv;               // this wave's tile index
    int n0 = widx << 8;
    int s0 = widx << 6, u0 = widx << 5, v0 = widx << 4, h0 = widx << 7;
    float* W = S + wv * WSTR;

    const float* x4row = x4 + (size_t)row * t8;
    const float* r3row = r3 + (size_t)row * t16;
    const float* i3row = i3 + (size_t)row * t16;
    const float* r2row = r2 + (size_t)row * t8;
    const float* i2row = i2 + (size_t)row * t8;
    const float* r1row = r1 + (size_t)row * t4;
    const float* i1row = i1 + (size_t)row * t4;
    const float* r0row = r0 + (size_t)row * t2;
    const float* i0row = i0 + (size_t)row * t2;
    bool bnd = (widx == 0) || (widx == NT256 - 1);

    // ---- hoisted epilogue loads: rA[e] = r0[h0 + 2*lane - 1 + e], e=0..3 ----
    float rA[4], iA[4];
    {
        int u0e = h0 + 2 * lane - 1;
        if (!bnd) {
            float4 va = *reinterpret_cast<const float4*>(r0row + u0e);
            float4 vb = *reinterpret_cast<const float4*>(i0row + u0e);
            rA[0] = va.x; rA[1] = va.y; rA[2] = va.z; rA[3] = va.w;
            iA[0] = vb.x; iA[1] = vb.y; iA[2] = vb.z; iA[3] = vb.w;
        } else {
#pragma unroll
            for (int e = 0; e < 4; ++e) {
                rA[e] = ldz(r0row, u0e + e, t2);
                iA[e] = ldz(i0row, u0e + e, t2);
            }
        }
    }

    // ---- stage this wave's halo windows: 80 float4 slots, 2 per lane ----
    // slot i: i<12 x4w | <18 r3 | <24 i3 | <34 r2 | <44 i2 | <62 r1 | <80 i1
    {
#pragma unroll
        for (int s = 0; s < 2; ++s) {
            int i = lane + 64 * s;
            if (s == 1 && lane >= 16) break;
            const float* src; int k, gb, len, doff;
            if (i < 12)      { src = x4row; k = i;      gb = 2*v0 - 8 + 4*k; len = t8;  doff = O_X4 + 4*k; }
            else if (i < 18) { src = r3row; k = i - 12; gb = v0 - 4 + 4*k;   len = t16; doff = O_R3 + 4*k; }
            else if (i < 24) { src = i3row; k = i - 18; gb = v0 - 4 + 4*k;   len = t16; doff = O_I3 + 4*k; }
            else if (i < 34) { src = r2row; k = i - 24; gb = u0 - 4 + 4*k;   len = t8;  doff = O_R2 + 4*k; }
            else if (i < 44) { src = i2row; k = i - 34; gb = u0 - 4 + 4*k;   len = t8;  doff = O_I2 + 4*k; }
            else if (i < 62) { src = r1row; k = i - 44; gb = s0 - 4 + 4*k;   len = t4;  doff = O_R1 + 4*k; }
            else             { src = i1row; k = i - 62; gb = s0 - 4 + 4*k;   len = t4;  doff = O_I1 + 4*k; }
            float4 v;
            if (!bnd) v = *reinterpret_cast<const float4*>(src + gb);
            else { v.x = ldz(src, gb, len); v.y = ldz(src, gb + 1, len);
                   v.z = ldz(src, gb + 2, len); v.w = ldz(src, gb + 3, len); }
            *reinterpret_cast<float4*>(W + doff) = v;
        }
    }

    QFilt f = load_qfilt(g0a, g0b, g1a, g1b);
    float g0r[7], g1r[5];
#pragma unroll
    for (int j = 0; j < 7; ++j) g0r[j] = g0o[j];
#pragma unroll
    for (int j = 0; j < 5; ++j) g1r[j] = S2 * g1o[j];

    WAVE_SYNC();

    // ---- phase A: 20 x3-quads (lanes 0..19). quad v = v0-2+k. ----
    if (lane < 20) {
        int k = lane;
        float4 q = quad_w(W, O_X4 + 2 * k, O_R3 + k, 24, f);
        if (bnd) {
            int v = v0 - 2 + k;
            if (v < 0 || v >= t16) q = make_float4(0.f, 0.f, 0.f, 0.f);
        }
        *reinterpret_cast<float4*>(W + O_X3 + 4 * k) = q;
    }
    WAVE_SYNC();

    // ---- phase B: 36 x2-quads (lanes 0..35). quad u = u0-2+k. ----
    if (lane < 36) {
        int k = lane;
        float4 q = quad_w(W, O_X3 + 2 * k, O_R2 + k, 40, f);
        if (bnd) {
            int u = u0 - 2 + k;
            if (u < 0 || u >= t8) q = make_float4(0.f, 0.f, 0.f, 0.f);
        }
        *reinterpret_cast<float4*>(W + O_X2 + 4 * k) = q;
    }
    WAVE_SYNC();

    // ---- phase C: 66 x1-quads. quad s = s0-1+l; lanes do l=lane (+2 extra). ----
    float4 myq;
    {
        int l = lane;
        float4 q = quad_w(W, O_X2 + 2 * l + 2, O_R1 + l + 1, 72, f);
        if (bnd) {
            int s = s0 - 1 + l;
            if (s < 0 || s >= t4) q = make_float4(0.f, 0.f, 0.f, 0.f);
        }
        myq = q;
        *reinterpret_cast<float4*>(W + O_X1 + 4 * l) = q;
        if (lane < 2) {
            int l2 = 64 + lane;
            q = quad_w(W, O_X2 + 2 * l2 + 2, O_R1 + l2 + 1, 72, f);
            if (bnd) {
                int s = s0 - 1 + l2;
                if (s < 0 || s >= t4) q = make_float4(0.f, 0.f, 0.f, 0.f);
            }
            *reinterpret_cast<float4*>(W + O_X1 + 4 * l2) = q;
        }
    }
    WAVE_SYNC();

    // ---- phase D: epilogue. w[d] = x1[n0-4+4*lane+d]; own quad in regs. ----
    float w[12];
    *reinterpret_cast<float4*>(&w[0]) = myq;
    *reinterpret_cast<float4*>(&w[4]) = *reinterpret_cast<float4*>(W + O_X1 + 4 * (lane + 1));
    *reinterpret_cast<float4*>(&w[8]) = *reinterpret_cast<float4*>(W + O_X1 + 4 * (lane + 2));

    float o[4];
#pragma unroll
    for (int p = 0; p < 4; ++p) {
        float acc = 0.f;
#pragma unroll
        for (int j = 0; j < 7; ++j)          // x1[n+3-j] -> w[p+7-j]
            acc = fmaf(g0r[j], w[p + 7 - j], acc);
#pragma unroll
        for (int j = 0; j < 5; ++j) {        // hi0[n+2-j] -> e = p+4-j
            int e = p + 4 - j;
            float v = (e & 1) ? iA[e >> 1] : rA[e >> 1];
            acc = fmaf(g1r[j], v, acc);
        }
        o[p] = acc;
    }
    reinterpret_cast<float4*>(out + (size_t)row * T_)[s0 + lane] =
        make_float4(o[0], o[1], o[2], o[3]);
}

extern "C" void kernel_launch(void* const* d_in, const int* in_sizes, int n_in,
                              void* d_out, int out_size, void* d_ws, size_t ws_size,
                              hipStream_t stream)
{
    const float* yl = (const float*)d_in[0];
    const float* yhr[8]; const float* yhi[8];
    for (int j = 0; j < 8; ++j) {
        yhr[j] = (const float*)d_in[1 + 2 * j];
        yhi[j] = (const float*)d_in[2 + 2 * j];
    }
    const float* g0o = (const float*)d_in[17];
    const float* g1o = (const float*)d_in[18];
    const float* g0a = (const float*)d_in[19];
    const float* g0b = (const float*)d_in[20];
    const float* g1a = (const float*)d_in[21];
    const float* g1b = (const float*)d_in[22];

    const int BC = 32 * 4;
    const int T_ = 262144;

    // Scratch: final reads x4 while writing the FULL d_out, so x4/x6 live in ws.
    float* x4buf = (float*)d_ws;
    float* x6buf = (float*)((char*)d_ws + ((size_t)32 << 20));

    // K76: yl + yh7 + yh6 -> x6 (L = 8192)
    {
        dim3 grid(8192 / 1024, BC);
        pair_lvl<<<grid, BLOCK, 0, stream>>>(
            yl, yhr[7], yhi[7], yhr[6], yhi[6], x6buf,
            g0a, g0b, g1a, g1b, 8192);
    }
    // K54: x6 + yh5 + yh4 -> x4 (L = 32768)
    {
        dim3 grid(32768 / 1024, BC);
        pair_lvl<<<grid, BLOCK, 0, stream>>>(
            x6buf, yhr[5], yhi[5], yhr[4], yhi[4], x4buf,
            g0a, g0b, g1a, g1b, 32768);
    }
    // final4_wave: x4 + yh3..yh0 -> out. 4 autonomous waves/block, 256 out/wave.
    dim3 grid((T_ >> 8) / 4, BC);
    final4_wave<<<grid, BLOCK, 0, stream>>>(
        x4buf, yhr[3], yhi[3], yhr[2], yhi[2], yhr[1], yhi[1],
        yhr[0], yhi[0], (float*)d_out,
        g0a, g0b, g1a, g1b, g0o, g1o, T_);
}

// Round 5
// 118.379 us; speedup vs baseline: 1.2296x; 1.2296x over previous
//
#include <hip/hip_runtime.h>

#define BLOCK 256
#define FT 1024           // output elements per tile (final kernel)

static __device__ __forceinline__ float ldz(const float* __restrict__ p, int i, int n) {
    return (i >= 0 && i < n) ? p[i] : 0.f;
}

// Phase barrier WITHOUT vmcnt drain: LDS visibility across waves needs
// lgkmcnt only. Keeps the rA/iA epilogue global loads in flight across
// phases A..C (__syncthreads' vmcnt(0) was draining them at barrier 1).
#define BAR_LGKM() do { \
    asm volatile("s_waitcnt lgkmcnt(0)" ::: "memory"); \
    __builtin_amdgcn_s_barrier(); \
} while (0)

// Full drain barrier (stage): global_load_lds completions are counted by
// vmcnt, so LDS visibility of the staged data needs vmcnt(0) here.
#define BAR_FULL() do { \
    asm volatile("s_waitcnt vmcnt(0) lgkmcnt(0)" ::: "memory"); \
    __builtin_amdgcn_s_barrier(); \
} while (0)

#define AS1C(p) ((const __attribute__((address_space(1))) unsigned int*)(p))
#define AS3(p)  ((__attribute__((address_space(3))) unsigned int*)(p))

// Quad-filter taps, reversed/deinterleaved, sqrt2 folded into the highpass set.
struct QFilt {
    float b0e[5], b0o[5], a0e[5], a0o[5];
    float b1e[5], b1o[5], a1e[5], a1o[5];
};

static __device__ __forceinline__ QFilt load_qfilt(
    const float* __restrict__ g0a, const float* __restrict__ g0b,
    const float* __restrict__ g1a, const float* __restrict__ g1b) {
    const float S2 = 1.4142135623730951f;
    QFilt f;
#pragma unroll
    for (int i = 0; i < 5; ++i) {
        f.b0e[i] = g0b[8 - 2 * i]; f.b0o[i] = g0b[9 - 2 * i];
        f.a0e[i] = g0a[8 - 2 * i]; f.a0o[i] = g0a[9 - 2 * i];
        f.b1e[i] = S2 * g1b[8 - 2 * i]; f.b1o[i] = S2 * g1b[9 - 2 * i];
        f.a1e[i] = S2 * g1a[8 - 2 * i]; f.a1o[i] = S2 * g1a[9 - 2 * i];
    }
    return f;
}

// Quad out[4s..4s+3]. Inputs relative to ONE LDS base so the backend merges:
// lo as float2 (ds_read_b64), r/i pair at constant dword distance ioff
// (ds_read2_b32 when ioff <= 255).
static __device__ __forceinline__ float4 quad_w(
    const float* base, int loOff, int riOff, int ioff, const QFilt& f) {
    float y0 = 0.f, y1 = 0.f, y2 = 0.f, y3 = 0.f;
#pragma unroll
    for (int i = 0; i < 5; ++i) {
        float2 lo2 = *reinterpret_cast<const float2*>(base + loOff + 2 * i);
        float ve = lo2.x, vo = lo2.y;
        float vr = base[riOff + i], vi = base[riOff + ioff + i];
        y0 = fmaf(ve, f.b0e[i], y0); y2 = fmaf(ve, f.b0o[i], y2);
        y1 = fmaf(vo, f.a0e[i], y1); y3 = fmaf(vo, f.a0o[i], y3);
        y0 = fmaf(vr, f.b1e[i], y0); y2 = fmaf(vr, f.b1o[i], y2);
        y1 = fmaf(vi, f.a1e[i], y1); y3 = fmaf(vi, f.a1o[i], y3);
    }
    return make_float4(y0, y1, y2, y3);
}

// Interleaved-window quad (pair_lvl only, unchanged).
static __device__ __forceinline__ float4 quad_i(
    const float* __restrict__ lo_s, int lobase,
    const float* __restrict__ r_s, const float* __restrict__ i_s, int ribase,
    const QFilt& f) {
    float y0 = 0.f, y1 = 0.f, y2 = 0.f, y3 = 0.f;
#pragma unroll
    for (int i = 0; i < 5; ++i) {
        float ve = lo_s[lobase + 2 * i], vo = lo_s[lobase + 2 * i + 1];
        float vr = r_s[ribase + i], vi = i_s[ribase + i];
        y0 = fmaf(ve, f.b0e[i], y0); y2 = fmaf(ve, f.b0o[i], y2);
        y1 = fmaf(vo, f.a0e[i], y1); y3 = fmaf(vo, f.a0o[i], y3);
        y0 = fmaf(vr, f.b1e[i], y0); y2 = fmaf(vr, f.b1o[i], y2);
        y1 = fmaf(vi, f.a1e[i], y1); y3 = fmaf(vi, f.a1o[i], y3);
    }
    return make_float4(y0, y1, y2, y3);
}

static __device__ __forceinline__ float4 quad_d(
    const float* __restrict__ Ae, const float* __restrict__ Ao, int base,
    const float* __restrict__ r_s, const float* __restrict__ i_s, int ribase,
    const QFilt& f) {
    float y0 = 0.f, y1 = 0.f, y2 = 0.f, y3 = 0.f;
#pragma unroll
    for (int i = 0; i < 5; ++i) {
        float ve = Ae[base + i], vo = Ao[base + i];
        float vr = r_s[ribase + i], vi = i_s[ribase + i];
        y0 = fmaf(ve, f.b0e[i], y0); y2 = fmaf(ve, f.b0o[i], y2);
        y1 = fmaf(vo, f.a0e[i], y1); y3 = fmaf(vo, f.a0o[i], y3);
        y0 = fmaf(vr, f.b1e[i], y0); y2 = fmaf(vr, f.b1o[i], y2);
        y1 = fmaf(vi, f.a1e[i], y1); y3 = fmaf(vi, f.a1o[i], y3);
    }
    return make_float4(y0, y1, y2, y3);
}

// TWO fused coarse levels (R11 structure, unchanged — measured near floor).
__global__ void __launch_bounds__(BLOCK) pair_lvl(
    const float* __restrict__ up,
    const float* __restrict__ ru, const float* __restrict__ iu,
    const float* __restrict__ rl, const float* __restrict__ il,
    float* __restrict__ out,
    const float* __restrict__ g0a, const float* __restrict__ g0b,
    const float* __restrict__ g1a, const float* __restrict__ g1b,
    int L)
{
    __shared__ __align__(16) float upw[272], ruw[140], iuw[140], rlw[264], ilw[264];
    __shared__ __align__(16) float Ae[260], Ao[260];
    int tid = threadIdx.x, bx = blockIdx.x, row = blockIdx.y;
    int lup = L >> 2, lu8 = L >> 3, lql = L >> 2;
    const float* uprow = up + (size_t)row * lup;
    const float* rurow = ru + (size_t)row * lu8;
    const float* iurow = iu + (size_t)row * lu8;
    const float* rlrow = rl + (size_t)row * lql;
    const float* ilrow = il + (size_t)row * lql;
    bool bnd = (bx == 0) || (bx == (int)gridDim.x - 1);
    int S = bx << 8;
    int sAu = (S >> 1) - 1;
    int gu = S - 8;
    int gru = (S >> 1) - 4;
    int grl = S - 4;

    for (int i = tid; i < 270; i += BLOCK) {
        const float* src; float* dst; int k, gb, len;
        if (i < 68)       { src = uprow; dst = upw; k = i;       gb = gu + 4 * k;  len = lup; }
        else if (i < 103) { src = rurow; dst = ruw; k = i - 68;  gb = gru + 4 * k; len = lu8; }
        else if (i < 138) { src = iurow; dst = iuw; k = i - 103; gb = gru + 4 * k; len = lu8; }
        else if (i < 204) { src = rlrow; dst = rlw; k = i - 138; gb = grl + 4 * k; len = lql; }
        else              { src = ilrow; dst = ilw; k = i - 204; gb = grl + 4 * k; len = lql; }
        float4 v;
        if (!bnd) v = *reinterpret_cast<const float4*>(src + gb);
        else { v.x = ldz(src, gb, len); v.y = ldz(src, gb + 1, len);
               v.z = ldz(src, gb + 2, len); v.w = ldz(src, gb + 3, len); }
        *reinterpret_cast<float4*>(dst + 4 * k) = v;
    }
    __syncthreads();

    QFilt f = load_qfilt(g0a, g0b, g1a, g1b);
    if (tid < 130) {
        float4 q = quad_i(upw, 2 * tid + 2, ruw, iuw, tid + 1, f);
        if (bnd) {
            int sp = sAu + tid;
            if (sp < 0 || sp >= lu8) q = make_float4(0.f, 0.f, 0.f, 0.f);
        }
        Ae[2 * tid] = q.x; Ae[2 * tid + 1] = q.z;
        Ao[2 * tid] = q.y; Ao[2 * tid + 1] = q.w;
    }
    __syncthreads();

    float4 res = quad_d(Ae, Ao, tid, rlw, ilw, tid + 2, f);
    reinterpret_cast<float4*>(out + (size_t)row * L)[S + tid] = res;
}

// ---- R17 final kernel: R14's proven block-phase structure with
// (1) async stage via global_load_lds (no VGPR round-trip; the 277 float4
//     slots are wave-linear: dest = W + 16B*slot),
// (2) rA/iA epilogue loads issued AFTER the stage barrier + lgkm-only phase
//     barriers, so they stay in flight under phases A..C,
// (3) merged-read quads (float2 lo, ds_read2-able r/i for phases A/B).
// Packed LDS map (dword offsets into W; slot i stages to W[4i..4i+3]):
#define O_X4 0      // x4  [148]  slots   0..36
#define O_R3 148    // yh3r [76]  slots  37..55   (i3 at +76)
#define O_I3 224    // yh3i [76]  slots  56..74
#define O_R2 300    // yh2r [140] slots  75..109  (i2 at +140)
#define O_I2 440    // yh2i [140] slots 110..144
#define O_R1 580    // yh1r [264] slots 145..210  (i1 at +264)
#define O_I1 844    // yh1i [264] slots 211..276
#define O_X3 1108   // x3 values [280]
#define O_X2 1388   // x2 values [528]
#define O_X1 1916   // x1 quads  [1032]
#define W_TOT 2948  // dwords = 11792 B

static __device__ __forceinline__ void slot_map(
    int i, int v0, int u0, int s0, int t4, int t8, int t16,
    const float* x4row, const float* r3row, const float* i3row,
    const float* r2row, const float* i2row,
    const float* r1row, const float* i1row,
    const float*& src, int& gb, int& len)
{
    if (i < 37)       { src = x4row; int k = i;       gb = 2 * v0 - 8 + 4 * k; len = t8;  }
    else if (i < 56)  { src = r3row; int k = i - 37;  gb = v0 - 4 + 4 * k;     len = t16; }
    else if (i < 75)  { src = i3row; int k = i - 56;  gb = v0 - 4 + 4 * k;     len = t16; }
    else if (i < 110) { src = r2row; int k = i - 75;  gb = u0 - 4 + 4 * k;     len = t8;  }
    else if (i < 145) { src = i2row; int k = i - 110; gb = u0 - 4 + 4 * k;     len = t8;  }
    else if (i < 211) { src = r1row; int k = i - 145; gb = s0 - 4 + 4 * k;     len = t4;  }
    else              { src = i1row; int k = i - 211; gb = s0 - 4 + 4 * k;     len = t4;  }
}

__global__ void __launch_bounds__(BLOCK) final4_async(
    const float* __restrict__ x4,                                 // T/8 per row
    const float* __restrict__ r3, const float* __restrict__ i3,   // T/16 per row
    const float* __restrict__ r2, const float* __restrict__ i2,   // T/8 per row
    const float* __restrict__ r1, const float* __restrict__ i1,   // T/4 per row
    const float* __restrict__ r0, const float* __restrict__ i0,   // T/2 per row
    float* __restrict__ out,                                      // T per row
    const float* __restrict__ g0a, const float* __restrict__ g0b,
    const float* __restrict__ g1a, const float* __restrict__ g1b,
    const float* __restrict__ g0o, const float* __restrict__ g1o,
    int T_)
{
    const float S2 = 1.4142135623730951f;
    __shared__ __align__(16) float W[W_TOT];

    int row = blockIdx.y, tid = threadIdx.x, bx = blockIdx.x;
    int t2 = T_ >> 1, t4 = T_ >> 2, t8 = T_ >> 3, t16 = T_ >> 4;
    int s0 = bx << 8, u0 = bx << 7, v0 = bx << 6, h0 = bx << 9;
    const float* x4row = x4 + (size_t)row * t8;
    const float* r3row = r3 + (size_t)row * t16;
    const float* i3row = i3 + (size_t)row * t16;
    const float* r2row = r2 + (size_t)row * t8;
    const float* i2row = i2 + (size_t)row * t8;
    const float* r1row = r1 + (size_t)row * t4;
    const float* i1row = i1 + (size_t)row * t4;
    const float* r0row = r0 + (size_t)row * t2;
    const float* i0row = i0 + (size_t)row * t2;
    bool bnd = (bx == 0) || (bx == (int)gridDim.x - 1);

    // ---- stage: 277 float4 slots, direct HBM -> LDS (wave-linear dest) ----
    if (!bnd) {
        {
            const float* src; int gb, len;
            slot_map(tid, v0, u0, s0, t4, t8, t16,
                     x4row, r3row, i3row, r2row, i2row, r1row, i1row, src, gb, len);
            __builtin_amdgcn_global_load_lds(AS1C(src + gb), AS3(W + 4 * tid), 16, 0, 0);
        }
        if (tid < 21) {
            const float* src; int gb, len;
            slot_map(tid + 256, v0, u0, s0, t4, t8, t16,
                     x4row, r3row, i3row, r2row, i2row, r1row, i1row, src, gb, len);
            __builtin_amdgcn_global_load_lds(AS1C(src + gb), AS3(W + 4 * (tid + 256)), 16, 0, 0);
        }
    } else {
#pragma unroll
        for (int it = 0; it < 2; ++it) {
            int i = tid + 256 * it;
            if (i < 277) {
                const float* src; int gb, len;
                slot_map(i, v0, u0, s0, t4, t8, t16,
                         x4row, r3row, i3row, r2row, i2row, r1row, i1row, src, gb, len);
                float4 v;
                v.x = ldz(src, gb, len);     v.y = ldz(src, gb + 1, len);
                v.z = ldz(src, gb + 2, len); v.w = ldz(src, gb + 3, len);
                *reinterpret_cast<float4*>(W + 4 * i) = v;
            }
        }
    }
    BAR_FULL();   // staged LDS data visible; nothing else in flight yet

    // ---- epilogue loads issued NOW: stay in flight under phases A..C ----
    float rA[4], iA[4];
    {
        int u0e = h0 + 2 * tid - 1;
        if (!bnd) {
            float4 va = *reinterpret_cast<const float4*>(r0row + u0e);
            float4 vb = *reinterpret_cast<const float4*>(i0row + u0e);
            rA[0] = va.x; rA[1] = va.y; rA[2] = va.z; rA[3] = va.w;
            iA[0] = vb.x; iA[1] = vb.y; iA[2] = vb.z; iA[3] = vb.w;
        } else {
#pragma unroll
            for (int e = 0; e < 4; ++e) {
                rA[e] = ldz(r0row, u0e + e, t2);
                iA[e] = ldz(i0row, u0e + e, t2);
            }
        }
    }

    QFilt f = load_qfilt(g0a, g0b, g1a, g1b);
    float g0r[7], g1r[5];
#pragma unroll
    for (int j = 0; j < 7; ++j) g0r[j] = g0o[j];
#pragma unroll
    for (int j = 0; j < 5; ++j) g1r[j] = S2 * g1o[j];

    // ---- phase A: 69 x3-quads. quad v = v0-2+k. ----
    if (tid < 69) {
        int k = tid;
        float4 q = quad_w(W, O_X4 + 2 * k, O_R3 + k, 76, f);
        if (bnd) {
            int v = v0 - 2 + k;
            if (v < 0 || v >= t16) q = make_float4(0.f, 0.f, 0.f, 0.f);
        }
        *reinterpret_cast<float4*>(W + O_X3 + 4 * k) = q;
    }
    BAR_LGKM();

    // ---- phase B: 132 x2-quads. quad u = u0-2+k. ----
    if (tid < 132) {
        int k = tid;
        float4 q = quad_w(W, O_X3 + 2 * k, O_R2 + k, 140, f);
        if (bnd) {
            int u = u0 - 2 + k;
            if (u < 0 || u >= t8) q = make_float4(0.f, 0.f, 0.f, 0.f);
        }
        *reinterpret_cast<float4*>(W + O_X2 + 4 * k) = q;
    }
    BAR_LGKM();

    // ---- phase C: 258 x1-quads. quad s = s0-1+l. ----
    float4 myq;
    {
        int l = tid;
        float4 q = quad_w(W, O_X2 + 2 * l + 2, O_R1 + l + 1, 264, f);
        if (bnd) {
            int s = s0 - 1 + l;
            if (s < 0 || s >= t4) q = make_float4(0.f, 0.f, 0.f, 0.f);
        }
        myq = q;
        *reinterpret_cast<float4*>(W + O_X1 + 4 * l) = q;
        if (tid < 2) {
            int l2 = 256 + tid;
            q = quad_w(W, O_X2 + 2 * l2 + 2, O_R1 + l2 + 1, 264, f);
            if (bnd) {
                int s = s0 - 1 + l2;
                if (s < 0 || s >= t4) q = make_float4(0.f, 0.f, 0.f, 0.f);
            }
            *reinterpret_cast<float4*>(W + O_X1 + 4 * l2) = q;
        }
    }
    BAR_LGKM();

    // ---- phase D: epilogue. w[d] = x1[n0-4+4*tid+d]; own quad in regs. ----
    float w[12];
    *reinterpret_cast<float4*>(&w[0]) = myq;
    *reinterpret_cast<float4*>(&w[4]) = *reinterpret_cast<const float4*>(W + O_X1 + 4 * (tid + 1));
    *reinterpret_cast<float4*>(&w[8]) = *reinterpret_cast<const float4*>(W + O_X1 + 4 * (tid + 2));

    float o[4];
#pragma unroll
    for (int p = 0; p < 4; ++p) {
        float acc = 0.f;
#pragma unroll
        for (int j = 0; j < 7; ++j)          // x1[n+3-j] -> w[p+7-j]
            acc = fmaf(g0r[j], w[p + 7 - j], acc);
#pragma unroll
        for (int j = 0; j < 5; ++j) {        // hi0[n+2-j] -> e = p+4-j
            int e = p + 4 - j;
            float v = (e & 1) ? iA[e >> 1] : rA[e >> 1];
            acc = fmaf(g1r[j], v, acc);
        }
        o[p] = acc;
    }
    reinterpret_cast<float4*>(out + (size_t)row * T_)[s0 + tid] =
        make_float4(o[0], o[1], o[2], o[3]);
}

extern "C" void kernel_launch(void* const* d_in, const int* in_sizes, int n_in,
                              void* d_out, int out_size, void* d_ws, size_t ws_size,
                              hipStream_t stream)
{
    const float* yl = (const float*)d_in[0];
    const float* yhr[8]; const float* yhi[8];
    for (int j = 0; j < 8; ++j) {
        yhr[j] = (const float*)d_in[1 + 2 * j];
        yhi[j] = (const float*)d_in[2 + 2 * j];
    }
    const float* g0o = (const float*)d_in[17];
    const float* g1o = (const float*)d_in[18];
    const float* g0a = (const float*)d_in[19];
    const float* g0b = (const float*)d_in[20];
    const float* g1a = (const float*)d_in[21];
    const float* g1b = (const float*)d_in[22];

    const int BC = 32 * 4;
    const int T_ = 262144;

    // Scratch: final reads x4 while writing the FULL d_out, so x4/x6 live in ws.
    float* x4buf = (float*)d_ws;
    float* x6buf = (float*)((char*)d_ws + ((size_t)32 << 20));

    // K76: yl + yh7 + yh6 -> x6 (L = 8192)
    {
        dim3 grid(8192 / 1024, BC);
        pair_lvl<<<grid, BLOCK, 0, stream>>>(
            yl, yhr[7], yhi[7], yhr[6], yhi[6], x6buf,
            g0a, g0b, g1a, g1b, 8192);
    }
    // K54: x6 + yh5 + yh4 -> x4 (L = 32768)
    {
        dim3 grid(32768 / 1024, BC);
        pair_lvl<<<grid, BLOCK, 0, stream>>>(
            x6buf, yhr[5], yhi[5], yhr[4], yhi[4], x4buf,
            g0a, g0b, g1a, g1b, 32768);
    }
    // final4_async: x4 + yh3..yh0 -> out (4 levels fused, async stage)
    dim3 grid(T_ / FT, BC);
    final4_async<<<grid, BLOCK, 0, stream>>>(
        x4buf, yhr[3], yhi[3], yhr[2], yhi[2], yhr[1], yhi[1],
        yhr[0], yhi[0], (float*)d_out,
        g0a, g0b, g1a, g1b, g0o, g1o, T_);
}

// Round 6
// 110.807 us; speedup vs baseline: 1.3137x; 1.0683x over previous
//
#include <hip/hip_runtime.h>

#define BLOCK 256
#define FT 1024           // output elements per tile (final kernel)

typedef float v2f __attribute__((ext_vector_type(2)));

static __device__ __forceinline__ float ldz(const float* __restrict__ p, int i, int n) {
    return (i >= 0 && i < n) ? p[i] : 0.f;
}

// Phase barrier WITHOUT vmcnt drain: LDS visibility across waves needs
// lgkmcnt only. Keeps the rA/iA epilogue global loads in flight across
// phases A..C.
#define BAR_LGKM() do { \
    asm volatile("s_waitcnt lgkmcnt(0)" ::: "memory"); \
    __builtin_amdgcn_s_barrier(); \
} while (0)

// Full drain barrier (stage): global_load_lds completions are counted by
// vmcnt, so LDS visibility of the staged data needs vmcnt(0) here.
#define BAR_FULL() do { \
    asm volatile("s_waitcnt vmcnt(0) lgkmcnt(0)" ::: "memory"); \
    __builtin_amdgcn_s_barrier(); \
} while (0)

#define AS1C(p) ((const __attribute__((address_space(1))) unsigned int*)(p))
#define AS3(p)  ((__attribute__((address_space(3))) unsigned int*)(p))

// ---- scalar filter set (pair_lvl only) ----
struct QFilt {
    float b0e[5], b0o[5], a0e[5], a0o[5];
    float b1e[5], b1o[5], a1e[5], a1o[5];
};

static __device__ __forceinline__ QFilt load_qfilt(
    const float* __restrict__ g0a, const float* __restrict__ g0b,
    const float* __restrict__ g1a, const float* __restrict__ g1b) {
    const float S2 = 1.4142135623730951f;
    QFilt f;
#pragma unroll
    for (int i = 0; i < 5; ++i) {
        f.b0e[i] = g0b[8 - 2 * i]; f.b0o[i] = g0b[9 - 2 * i];
        f.a0e[i] = g0a[8 - 2 * i]; f.a0o[i] = g0a[9 - 2 * i];
        f.b1e[i] = S2 * g1b[8 - 2 * i]; f.b1o[i] = S2 * g1b[9 - 2 * i];
        f.a1e[i] = S2 * g1a[8 - 2 * i]; f.a1o[i] = S2 * g1a[9 - 2 * i];
    }
    return f;
}

// ---- R18: packed filter set (final4). Pairs arranged so the LOADED data
// feeds v_pk_fma_f32 with no broadcasts:
//   y01=(y0,y1) += (ve,vo)*(b0e,a0e) + (vr,vi)*(b1e,a1e)
//   y23=(y2,y3) += (ve,vo)*(b0o,a0o) + (vr,vi)*(b1o,a1o)
struct QFiltP {
    v2f f01l[5], f23l[5], f01h[5], f23h[5];
};

static __device__ __forceinline__ QFiltP load_qfiltp(
    const float* __restrict__ g0a, const float* __restrict__ g0b,
    const float* __restrict__ g1a, const float* __restrict__ g1b) {
    const float S2 = 1.4142135623730951f;
    QFiltP f;
#pragma unroll
    for (int i = 0; i < 5; ++i) {
        float b0e = g0b[8 - 2 * i], b0o = g0b[9 - 2 * i];
        float a0e = g0a[8 - 2 * i], a0o = g0a[9 - 2 * i];
        float b1e = S2 * g1b[8 - 2 * i], b1o = S2 * g1b[9 - 2 * i];
        float a1e = S2 * g1a[8 - 2 * i], a1o = S2 * g1a[9 - 2 * i];
        f.f01l[i] = (v2f){b0e, a0e};
        f.f23l[i] = (v2f){b0o, a0o};
        f.f01h[i] = (v2f){b1e, a1e};
        f.f23h[i] = (v2f){b1o, a1o};
    }
    return f;
}

// Packed quad: out[4s..4s+3]. lo window as float2 loads (ds_read_b64),
// r/i pair as two b32 (mergeable to ds_read2_b32 when ioff<=255) landing in
// an aligned VGPR pair. 20 v_pk_fma_f32 instead of 40 v_fma_f32.
static __device__ __forceinline__ float4 quad_p(
    const float* base, int loOff, int riOff, int ioff, const QFiltP& f) {
    v2f y01 = (v2f){0.f, 0.f}, y23 = (v2f){0.f, 0.f};
#pragma unroll
    for (int i = 0; i < 5; ++i) {
        v2f lo2 = *reinterpret_cast<const v2f*>(base + loOff + 2 * i);
        v2f ri;
        ri.x = base[riOff + i];
        ri.y = base[riOff + ioff + i];
        y01 = __builtin_elementwise_fma(lo2, f.f01l[i], y01);
        y23 = __builtin_elementwise_fma(lo2, f.f23l[i], y23);
        y01 = __builtin_elementwise_fma(ri, f.f01h[i], y01);
        y23 = __builtin_elementwise_fma(ri, f.f23h[i], y23);
    }
    return make_float4(y01.x, y01.y, y23.x, y23.y);
}

// Interleaved-window quad (pair_lvl only, unchanged).
static __device__ __forceinline__ float4 quad_i(
    const float* __restrict__ lo_s, int lobase,
    const float* __restrict__ r_s, const float* __restrict__ i_s, int ribase,
    const QFilt& f) {
    float y0 = 0.f, y1 = 0.f, y2 = 0.f, y3 = 0.f;
#pragma unroll
    for (int i = 0; i < 5; ++i) {
        float ve = lo_s[lobase + 2 * i], vo = lo_s[lobase + 2 * i + 1];
        float vr = r_s[ribase + i], vi = i_s[ribase + i];
        y0 = fmaf(ve, f.b0e[i], y0); y2 = fmaf(ve, f.b0o[i], y2);
        y1 = fmaf(vo, f.a0e[i], y1); y3 = fmaf(vo, f.a0o[i], y3);
        y0 = fmaf(vr, f.b1e[i], y0); y2 = fmaf(vr, f.b1o[i], y2);
        y1 = fmaf(vi, f.a1e[i], y1); y3 = fmaf(vi, f.a1o[i], y3);
    }
    return make_float4(y0, y1, y2, y3);
}

static __device__ __forceinline__ float4 quad_d(
    const float* __restrict__ Ae, const float* __restrict__ Ao, int base,
    const float* __restrict__ r_s, const float* __restrict__ i_s, int ribase,
    const QFilt& f) {
    float y0 = 0.f, y1 = 0.f, y2 = 0.f, y3 = 0.f;
#pragma unroll
    for (int i = 0; i < 5; ++i) {
        float ve = Ae[base + i], vo = Ao[base + i];
        float vr = r_s[ribase + i], vi = i_s[ribase + i];
        y0 = fmaf(ve, f.b0e[i], y0); y2 = fmaf(ve, f.b0o[i], y2);
        y1 = fmaf(vo, f.a0e[i], y1); y3 = fmaf(vo, f.a0o[i], y3);
        y0 = fmaf(vr, f.b1e[i], y0); y2 = fmaf(vr, f.b1o[i], y2);
        y1 = fmaf(vi, f.a1e[i], y1); y3 = fmaf(vi, f.a1o[i], y3);
    }
    return make_float4(y0, y1, y2, y3);
}

// TWO fused coarse levels (R11 structure, unchanged — measured near floor).
__global__ void __launch_bounds__(BLOCK) pair_lvl(
    const float* __restrict__ up,
    const float* __restrict__ ru, const float* __restrict__ iu,
    const float* __restrict__ rl, const float* __restrict__ il,
    float* __restrict__ out,
    const float* __restrict__ g0a, const float* __restrict__ g0b,
    const float* __restrict__ g1a, const float* __restrict__ g1b,
    int L)
{
    __shared__ __align__(16) float upw[272], ruw[140], iuw[140], rlw[264], ilw[264];
    __shared__ __align__(16) float Ae[260], Ao[260];
    int tid = threadIdx.x, bx = blockIdx.x, row = blockIdx.y;
    int lup = L >> 2, lu8 = L >> 3, lql = L >> 2;
    const float* uprow = up + (size_t)row * lup;
    const float* rurow = ru + (size_t)row * lu8;
    const float* iurow = iu + (size_t)row * lu8;
    const float* rlrow = rl + (size_t)row * lql;
    const float* ilrow = il + (size_t)row * lql;
    bool bnd = (bx == 0) || (bx == (int)gridDim.x - 1);
    int S = bx << 8;
    int sAu = (S >> 1) - 1;
    int gu = S - 8;
    int gru = (S >> 1) - 4;
    int grl = S - 4;

    for (int i = tid; i < 270; i += BLOCK) {
        const float* src; float* dst; int k, gb, len;
        if (i < 68)       { src = uprow; dst = upw; k = i;       gb = gu + 4 * k;  len = lup; }
        else if (i < 103) { src = rurow; dst = ruw; k = i - 68;  gb = gru + 4 * k; len = lu8; }
        else if (i < 138) { src = iurow; dst = iuw; k = i - 103; gb = gru + 4 * k; len = lu8; }
        else if (i < 204) { src = rlrow; dst = rlw; k = i - 138; gb = grl + 4 * k; len = lql; }
        else              { src = ilrow; dst = ilw; k = i - 204; gb = grl + 4 * k; len = lql; }
        float4 v;
        if (!bnd) v = *reinterpret_cast<const float4*>(src + gb);
        else { v.x = ldz(src, gb, len); v.y = ldz(src, gb + 1, len);
               v.z = ldz(src, gb + 2, len); v.w = ldz(src, gb + 3, len); }
        *reinterpret_cast<float4*>(dst + 4 * k) = v;
    }
    __syncthreads();

    QFilt f = load_qfilt(g0a, g0b, g1a, g1b);
    if (tid < 130) {
        float4 q = quad_i(upw, 2 * tid + 2, ruw, iuw, tid + 1, f);
        if (bnd) {
            int sp = sAu + tid;
            if (sp < 0 || sp >= lu8) q = make_float4(0.f, 0.f, 0.f, 0.f);
        }
        Ae[2 * tid] = q.x; Ae[2 * tid + 1] = q.z;
        Ao[2 * tid] = q.y; Ao[2 * tid + 1] = q.w;
    }
    __syncthreads();

    float4 res = quad_d(Ae, Ao, tid, rlw, ilw, tid + 2, f);
    reinterpret_cast<float4*>(out + (size_t)row * L)[S + tid] = res;
}

// ---- final kernel: R17 structure (async stage + lgkm-only phase barriers)
// with R18 packed-fp32 quads (v_pk_fma_f32 via llvm.fma.v2f32).
// Packed LDS map (dword offsets into W; slot i stages to W[4i..4i+3]):
#define O_X4 0      // x4  [148]  slots   0..36
#define O_R3 148    // yh3r [76]  slots  37..55   (i3 at +76)
#define O_I3 224    // yh3i [76]  slots  56..74
#define O_R2 300    // yh2r [140] slots  75..109  (i2 at +140)
#define O_I2 440    // yh2i [140] slots 110..144
#define O_R1 580    // yh1r [264] slots 145..210  (i1 at +264)
#define O_I1 844    // yh1i [264] slots 211..276
#define O_X3 1108   // x3 values [280]
#define O_X2 1388   // x2 values [528]
#define O_X1 1916   // x1 quads  [1032]
#define W_TOT 2948  // dwords = 11792 B

static __device__ __forceinline__ void slot_map(
    int i, int v0, int u0, int s0, int t4, int t8, int t16,
    const float* x4row, const float* r3row, const float* i3row,
    const float* r2row, const float* i2row,
    const float* r1row, const float* i1row,
    const float*& src, int& gb, int& len)
{
    if (i < 37)       { src = x4row; int k = i;       gb = 2 * v0 - 8 + 4 * k; len = t8;  }
    else if (i < 56)  { src = r3row; int k = i - 37;  gb = v0 - 4 + 4 * k;     len = t16; }
    else if (i < 75)  { src = i3row; int k = i - 56;  gb = v0 - 4 + 4 * k;     len = t16; }
    else if (i < 110) { src = r2row; int k = i - 75;  gb = u0 - 4 + 4 * k;     len = t8;  }
    else if (i < 145) { src = i2row; int k = i - 110; gb = u0 - 4 + 4 * k;     len = t8;  }
    else if (i < 211) { src = r1row; int k = i - 145; gb = s0 - 4 + 4 * k;     len = t4;  }
    else              { src = i1row; int k = i - 211; gb = s0 - 4 + 4 * k;     len = t4;  }
}

__global__ void __launch_bounds__(BLOCK) final4_async(
    const float* __restrict__ x4,                                 // T/8 per row
    const float* __restrict__ r3, const float* __restrict__ i3,   // T/16 per row
    const float* __restrict__ r2, const float* __restrict__ i2,   // T/8 per row
    const float* __restrict__ r1, const float* __restrict__ i1,   // T/4 per row
    const float* __restrict__ r0, const float* __restrict__ i0,   // T/2 per row
    float* __restrict__ out,                                      // T per row
    const float* __restrict__ g0a, const float* __restrict__ g0b,
    const float* __restrict__ g1a, const float* __restrict__ g1b,
    const float* __restrict__ g0o, const float* __restrict__ g1o,
    int T_)
{
    const float S2 = 1.4142135623730951f;
    __shared__ __align__(16) float W[W_TOT];

    int row = blockIdx.y, tid = threadIdx.x, bx = blockIdx.x;
    int t2 = T_ >> 1, t4 = T_ >> 2, t8 = T_ >> 3, t16 = T_ >> 4;
    int s0 = bx << 8, u0 = bx << 7, v0 = bx << 6, h0 = bx << 9;
    const float* x4row = x4 + (size_t)row * t8;
    const float* r3row = r3 + (size_t)row * t16;
    const float* i3row = i3 + (size_t)row * t16;
    const float* r2row = r2 + (size_t)row * t8;
    const float* i2row = i2 + (size_t)row * t8;
    const float* r1row = r1 + (size_t)row * t4;
    const float* i1row = i1 + (size_t)row * t4;
    const float* r0row = r0 + (size_t)row * t2;
    const float* i0row = i0 + (size_t)row * t2;
    bool bnd = (bx == 0) || (bx == (int)gridDim.x - 1);

    // ---- stage: 277 float4 slots, direct HBM -> LDS (wave-linear dest) ----
    if (!bnd) {
        {
            const float* src; int gb, len;
            slot_map(tid, v0, u0, s0, t4, t8, t16,
                     x4row, r3row, i3row, r2row, i2row, r1row, i1row, src, gb, len);
            __builtin_amdgcn_global_load_lds(AS1C(src + gb), AS3(W + 4 * tid), 16, 0, 0);
        }
        if (tid < 21) {
            const float* src; int gb, len;
            slot_map(tid + 256, v0, u0, s0, t4, t8, t16,
                     x4row, r3row, i3row, r2row, i2row, r1row, i1row, src, gb, len);
            __builtin_amdgcn_global_load_lds(AS1C(src + gb), AS3(W + 4 * (tid + 256)), 16, 0, 0);
        }
    } else {
#pragma unroll
        for (int it = 0; it < 2; ++it) {
            int i = tid + 256 * it;
            if (i < 277) {
                const float* src; int gb, len;
                slot_map(i, v0, u0, s0, t4, t8, t16,
                         x4row, r3row, i3row, r2row, i2row, r1row, i1row, src, gb, len);
                float4 v;
                v.x = ldz(src, gb, len);     v.y = ldz(src, gb + 1, len);
                v.z = ldz(src, gb + 2, len); v.w = ldz(src, gb + 3, len);
                *reinterpret_cast<float4*>(W + 4 * i) = v;
            }
        }
    }
    BAR_FULL();   // staged LDS data visible; nothing else in flight yet

    // ---- epilogue loads issued NOW: stay in flight under phases A..C ----
    float rA[4], iA[4];
    {
        int u0e = h0 + 2 * tid - 1;
        if (!bnd) {
            float4 va = *reinterpret_cast<const float4*>(r0row + u0e);
            float4 vb = *reinterpret_cast<const float4*>(i0row + u0e);
            rA[0] = va.x; rA[1] = va.y; rA[2] = va.z; rA[3] = va.w;
            iA[0] = vb.x; iA[1] = vb.y; iA[2] = vb.z; iA[3] = vb.w;
        } else {
#pragma unroll
            for (int e = 0; e < 4; ++e) {
                rA[e] = ldz(r0row, u0e + e, t2);
                iA[e] = ldz(i0row, u0e + e, t2);
            }
        }
    }

    QFiltP f = load_qfiltp(g0a, g0b, g1a, g1b);
    float g0r[7], g1r[5];
#pragma unroll
    for (int j = 0; j < 7; ++j) g0r[j] = g0o[j];
#pragma unroll
    for (int j = 0; j < 5; ++j) g1r[j] = S2 * g1o[j];

    // ---- phase A: 69 x3-quads. quad v = v0-2+k. ----
    if (tid < 69) {
        int k = tid;
        float4 q = quad_p(W, O_X4 + 2 * k, O_R3 + k, 76, f);
        if (bnd) {
            int v = v0 - 2 + k;
            if (v < 0 || v >= t16) q = make_float4(0.f, 0.f, 0.f, 0.f);
        }
        *reinterpret_cast<float4*>(W + O_X3 + 4 * k) = q;
    }
    BAR_LGKM();

    // ---- phase B: 132 x2-quads. quad u = u0-2+k. ----
    if (tid < 132) {
        int k = tid;
        float4 q = quad_p(W, O_X3 + 2 * k, O_R2 + k, 140, f);
        if (bnd) {
            int u = u0 - 2 + k;
            if (u < 0 || u >= t8) q = make_float4(0.f, 0.f, 0.f, 0.f);
        }
        *reinterpret_cast<float4*>(W + O_X2 + 4 * k) = q;
    }
    BAR_LGKM();

    // ---- phase C: 258 x1-quads. quad s = s0-1+l. ----
    float4 myq;
    {
        int l = tid;
        float4 q = quad_p(W, O_X2 + 2 * l + 2, O_R1 + l + 1, 264, f);
        if (bnd) {
            int s = s0 - 1 + l;
            if (s < 0 || s >= t4) q = make_float4(0.f, 0.f, 0.f, 0.f);
        }
        myq = q;
        *reinterpret_cast<float4*>(W + O_X1 + 4 * l) = q;
        if (tid < 2) {
            int l2 = 256 + tid;
            q = quad_p(W, O_X2 + 2 * l2 + 2, O_R1 + l2 + 1, 264, f);
            if (bnd) {
                int s = s0 - 1 + l2;
                if (s < 0 || s >= t4) q = make_float4(0.f, 0.f, 0.f, 0.f);
            }
            *reinterpret_cast<float4*>(W + O_X1 + 4 * l2) = q;
        }
    }
    BAR_LGKM();

    // ---- phase D: epilogue. w[d] = x1[n0-4+4*tid+d]; own quad in regs. ----
    float w[12];
    *reinterpret_cast<float4*>(&w[0]) = myq;
    *reinterpret_cast<float4*>(&w[4]) = *reinterpret_cast<const float4*>(W + O_X1 + 4 * (tid + 1));
    *reinterpret_cast<float4*>(&w[8]) = *reinterpret_cast<const float4*>(W + O_X1 + 4 * (tid + 2));

    float o[4];
#pragma unroll
    for (int p = 0; p < 4; ++p) {
        float acc = 0.f;
#pragma unroll
        for (int j = 0; j < 7; ++j)          // x1[n+3-j] -> w[p+7-j]
            acc = fmaf(g0r[j], w[p + 7 - j], acc);
#pragma unroll
        for (int j = 0; j < 5; ++j) {        // hi0[n+2-j] -> e = p+4-j
            int e = p + 4 - j;
            float v = (e & 1) ? iA[e >> 1] : rA[e >> 1];
            acc = fmaf(g1r[j], v, acc);
        }
        o[p] = acc;
    }
    reinterpret_cast<float4*>(out + (size_t)row * T_)[s0 + tid] =
        make_float4(o[0], o[1], o[2], o[3]);
}

extern "C" void kernel_launch(void* const* d_in, const int* in_sizes, int n_in,
                              void* d_out, int out_size, void* d_ws, size_t ws_size,
                              hipStream_t stream)
{
    const float* yl = (const float*)d_in[0];
    const float* yhr[8]; const float* yhi[8];
    for (int j = 0; j < 8; ++j) {
        yhr[j] = (const float*)d_in[1 + 2 * j];
        yhi[j] = (const float*)d_in[2 + 2 * j];
    }
    const float* g0o = (const float*)d_in[17];
    const float* g1o = (const float*)d_in[18];
    const float* g0a = (const float*)d_in[19];
    const float* g0b = (const float*)d_in[20];
    const float* g1a = (const float*)d_in[21];
    const float* g1b = (const float*)d_in[22];

    const int BC = 32 * 4;
    const int T_ = 262144;

    // Scratch: final reads x4 while writing the FULL d_out, so x4/x6 live in ws.
    float* x4buf = (float*)d_ws;
    float* x6buf = (float*)((char*)d_ws + ((size_t)32 << 20));

    // K76: yl + yh7 + yh6 -> x6 (L = 8192)
    {
        dim3 grid(8192 / 1024, BC);
        pair_lvl<<<grid, BLOCK, 0, stream>>>(
            yl, yhr[7], yhi[7], yhr[6], yhi[6], x6buf,
            g0a, g0b, g1a, g1b, 8192);
    }
    // K54: x6 + yh5 + yh4 -> x4 (L = 32768)
    {
        dim3 grid(32768 / 1024, BC);
        pair_lvl<<<grid, BLOCK, 0, stream>>>(
            x6buf, yhr[5], yhi[5], yhr[4], yhi[4], x4buf,
            g0a, g0b, g1a, g1b, 32768);
    }
    // final4_async: x4 + yh3..yh0 -> out (4 levels fused, async stage, pk_fma)
    dim3 grid(T_ / FT, BC);
    final4_async<<<grid, BLOCK, 0, stream>>>(
        x4buf, yhr[3], yhi[3], yhr[2], yhi[2], yhr[1], yhi[1],
        yhr[0], yhi[0], (float*)d_out,
        g0a, g0b, g1a, g1b, g0o, g1o, T_);
}

// Round 7
// 106.901 us; speedup vs baseline: 1.3617x; 1.0365x over previous
//
#include <hip/hip_runtime.h>

#define PBLOCK 256        // pair_lvl block (unchanged structure)
#define FBLOCK 128        // R19: final kernel block = 2 waves
#define FT 512            // output elements per tile (final kernel)

typedef float v2f __attribute__((ext_vector_type(2)));

static __device__ __forceinline__ float ldz(const float* __restrict__ p, int i, int n) {
    return (i >= 0 && i < n) ? p[i] : 0.f;
}

// Phase barrier WITHOUT vmcnt drain: LDS visibility across waves needs
// lgkmcnt only. Keeps the rA/iA epilogue global loads in flight across
// phases A..C.
#define BAR_LGKM() do { \
    asm volatile("s_waitcnt lgkmcnt(0)" ::: "memory"); \
    __builtin_amdgcn_s_barrier(); \
} while (0)

// Full drain barrier (stage): global_load_lds completions are counted by
// vmcnt, so LDS visibility of the staged data needs vmcnt(0) here.
#define BAR_FULL() do { \
    asm volatile("s_waitcnt vmcnt(0) lgkmcnt(0)" ::: "memory"); \
    __builtin_amdgcn_s_barrier(); \
} while (0)

#define AS1C(p) ((const __attribute__((address_space(1))) unsigned int*)(p))
#define AS3(p)  ((__attribute__((address_space(3))) unsigned int*)(p))

// ---- scalar filter set (pair_lvl only) ----
struct QFilt {
    float b0e[5], b0o[5], a0e[5], a0o[5];
    float b1e[5], b1o[5], a1e[5], a1o[5];
};

static __device__ __forceinline__ QFilt load_qfilt(
    const float* __restrict__ g0a, const float* __restrict__ g0b,
    const float* __restrict__ g1a, const float* __restrict__ g1b) {
    const float S2 = 1.4142135623730951f;
    QFilt f;
#pragma unroll
    for (int i = 0; i < 5; ++i) {
        f.b0e[i] = g0b[8 - 2 * i]; f.b0o[i] = g0b[9 - 2 * i];
        f.a0e[i] = g0a[8 - 2 * i]; f.a0o[i] = g0a[9 - 2 * i];
        f.b1e[i] = S2 * g1b[8 - 2 * i]; f.b1o[i] = S2 * g1b[9 - 2 * i];
        f.a1e[i] = S2 * g1a[8 - 2 * i]; f.a1o[i] = S2 * g1a[9 - 2 * i];
    }
    return f;
}

// ---- packed filter set (final kernel) ----
struct QFiltP {
    v2f f01l[5], f23l[5], f01h[5], f23h[5];
};

static __device__ __forceinline__ QFiltP load_qfiltp(
    const float* __restrict__ g0a, const float* __restrict__ g0b,
    const float* __restrict__ g1a, const float* __restrict__ g1b) {
    const float S2 = 1.4142135623730951f;
    QFiltP f;
#pragma unroll
    for (int i = 0; i < 5; ++i) {
        float b0e = g0b[8 - 2 * i], b0o = g0b[9 - 2 * i];
        float a0e = g0a[8 - 2 * i], a0o = g0a[9 - 2 * i];
        float b1e = S2 * g1b[8 - 2 * i], b1o = S2 * g1b[9 - 2 * i];
        float a1e = S2 * g1a[8 - 2 * i], a1o = S2 * g1a[9 - 2 * i];
        f.f01l[i] = (v2f){b0e, a0e};
        f.f23l[i] = (v2f){b0o, a0o};
        f.f01h[i] = (v2f){b1e, a1e};
        f.f23h[i] = (v2f){b1o, a1o};
    }
    return f;
}

// Packed quad: out[4s..4s+3]. lo window as float2 loads (ds_read_b64),
// r/i pair as two b32 (mergeable to ds_read2_b32 when ioff<=255).
static __device__ __forceinline__ float4 quad_p(
    const float* base, int loOff, int riOff, int ioff, const QFiltP& f) {
    v2f y01 = (v2f){0.f, 0.f}, y23 = (v2f){0.f, 0.f};
#pragma unroll
    for (int i = 0; i < 5; ++i) {
        v2f lo2 = *reinterpret_cast<const v2f*>(base + loOff + 2 * i);
        v2f ri;
        ri.x = base[riOff + i];
        ri.y = base[riOff + ioff + i];
        y01 = __builtin_elementwise_fma(lo2, f.f01l[i], y01);
        y23 = __builtin_elementwise_fma(lo2, f.f23l[i], y23);
        y01 = __builtin_elementwise_fma(ri, f.f01h[i], y01);
        y23 = __builtin_elementwise_fma(ri, f.f23h[i], y23);
    }
    return make_float4(y01.x, y01.y, y23.x, y23.y);
}

// Interleaved-window quad (pair_lvl only, unchanged).
static __device__ __forceinline__ float4 quad_i(
    const float* __restrict__ lo_s, int lobase,
    const float* __restrict__ r_s, const float* __restrict__ i_s, int ribase,
    const QFilt& f) {
    float y0 = 0.f, y1 = 0.f, y2 = 0.f, y3 = 0.f;
#pragma unroll
    for (int i = 0; i < 5; ++i) {
        float ve = lo_s[lobase + 2 * i], vo = lo_s[lobase + 2 * i + 1];
        float vr = r_s[ribase + i], vi = i_s[ribase + i];
        y0 = fmaf(ve, f.b0e[i], y0); y2 = fmaf(ve, f.b0o[i], y2);
        y1 = fmaf(vo, f.a0e[i], y1); y3 = fmaf(vo, f.a0o[i], y3);
        y0 = fmaf(vr, f.b1e[i], y0); y2 = fmaf(vr, f.b1o[i], y2);
        y1 = fmaf(vi, f.a1e[i], y1); y3 = fmaf(vi, f.a1o[i], y3);
    }
    return make_float4(y0, y1, y2, y3);
}

static __device__ __forceinline__ float4 quad_d(
    const float* __restrict__ Ae, const float* __restrict__ Ao, int base,
    const float* __restrict__ r_s, const float* __restrict__ i_s, int ribase,
    const QFilt& f) {
    float y0 = 0.f, y1 = 0.f, y2 = 0.f, y3 = 0.f;
#pragma unroll
    for (int i = 0; i < 5; ++i) {
        float ve = Ae[base + i], vo = Ao[base + i];
        float vr = r_s[ribase + i], vi = i_s[ribase + i];
        y0 = fmaf(ve, f.b0e[i], y0); y2 = fmaf(ve, f.b0o[i], y2);
        y1 = fmaf(vo, f.a0e[i], y1); y3 = fmaf(vo, f.a0o[i], y3);
        y0 = fmaf(vr, f.b1e[i], y0); y2 = fmaf(vr, f.b1o[i], y2);
        y1 = fmaf(vi, f.a1e[i], y1); y3 = fmaf(vi, f.a1o[i], y3);
    }
    return make_float4(y0, y1, y2, y3);
}

// TWO fused coarse levels (R11 structure, unchanged — measured near floor).
__global__ void __launch_bounds__(PBLOCK) pair_lvl(
    const float* __restrict__ up,
    const float* __restrict__ ru, const float* __restrict__ iu,
    const float* __restrict__ rl, const float* __restrict__ il,
    float* __restrict__ out,
    const float* __restrict__ g0a, const float* __restrict__ g0b,
    const float* __restrict__ g1a, const float* __restrict__ g1b,
    int L)
{
    __shared__ __align__(16) float upw[272], ruw[140], iuw[140], rlw[264], ilw[264];
    __shared__ __align__(16) float Ae[260], Ao[260];
    int tid = threadIdx.x, bx = blockIdx.x, row = blockIdx.y;
    int lup = L >> 2, lu8 = L >> 3, lql = L >> 2;
    const float* uprow = up + (size_t)row * lup;
    const float* rurow = ru + (size_t)row * lu8;
    const float* iurow = iu + (size_t)row * lu8;
    const float* rlrow = rl + (size_t)row * lql;
    const float* ilrow = il + (size_t)row * lql;
    bool bnd = (bx == 0) || (bx == (int)gridDim.x - 1);
    int S = bx << 8;
    int sAu = (S >> 1) - 1;
    int gu = S - 8;
    int gru = (S >> 1) - 4;
    int grl = S - 4;

    for (int i = tid; i < 270; i += PBLOCK) {
        const float* src; float* dst; int k, gb, len;
        if (i < 68)       { src = uprow; dst = upw; k = i;       gb = gu + 4 * k;  len = lup; }
        else if (i < 103) { src = rurow; dst = ruw; k = i - 68;  gb = gru + 4 * k; len = lu8; }
        else if (i < 138) { src = iurow; dst = iuw; k = i - 103; gb = gru + 4 * k; len = lu8; }
        else if (i < 204) { src = rlrow; dst = rlw; k = i - 138; gb = grl + 4 * k; len = lql; }
        else              { src = ilrow; dst = ilw; k = i - 204; gb = grl + 4 * k; len = lql; }
        float4 v;
        if (!bnd) v = *reinterpret_cast<const float4*>(src + gb);
        else { v.x = ldz(src, gb, len); v.y = ldz(src, gb + 1, len);
               v.z = ldz(src, gb + 2, len); v.w = ldz(src, gb + 3, len); }
        *reinterpret_cast<float4*>(dst + 4 * k) = v;
    }
    __syncthreads();

    QFilt f = load_qfilt(g0a, g0b, g1a, g1b);
    if (tid < 130) {
        float4 q = quad_i(upw, 2 * tid + 2, ruw, iuw, tid + 1, f);
        if (bnd) {
            int sp = sAu + tid;
            if (sp < 0 || sp >= lu8) q = make_float4(0.f, 0.f, 0.f, 0.f);
        }
        Ae[2 * tid] = q.x; Ae[2 * tid + 1] = q.z;
        Ao[2 * tid] = q.y; Ao[2 * tid + 1] = q.w;
    }
    __syncthreads();

    float4 res = quad_d(Ae, Ao, tid, rlw, ilw, tid + 2, f);
    reinterpret_cast<float4*>(out + (size_t)row * L)[S + tid] = res;
}

// ---- R19 final kernel: R18 structure (async stage + lgkm-only barriers +
// packed quads) at HALF block granularity: 128 threads (2 waves), FT=512.
// Same waves/CU (16 blocks x 2 waves = 32) but barrier groups shrink 4->2
// waves and independent blocks double -> stall decorrelation.
// Packed LDS map (dword offsets into W; slot i stages to W[4i..4i+3]):
#define O_X4 0      // x4   [80]  slots   0..19
#define O_R3 80     // yh3r [40]  slots  20..29   (i3 at +40)
#define O_I3 120    // yh3i [40]  slots  30..39
#define O_R2 160    // yh2r [72]  slots  40..57   (i2 at +72)
#define O_I2 232    // yh2i [72]  slots  58..75
#define O_R1 304    // yh1r [136] slots  76..109  (i1 at +136)
#define O_I1 440    // yh1i [136] slots 110..143
#define O_X3 576    // x3 values [144]
#define O_X2 720    // x2 values [272]
#define O_X1 992    // x1 quads  [520]
#define W_TOT 1512  // dwords = 6048 B
#define NSLOT 144

static __device__ __forceinline__ void slot_map(
    int i, int v0, int u0, int s0, int t4, int t8, int t16,
    const float* x4row, const float* r3row, const float* i3row,
    const float* r2row, const float* i2row,
    const float* r1row, const float* i1row,
    const float*& src, int& gb, int& len)
{
    if (i < 20)       { src = x4row; int k = i;       gb = 2 * v0 - 8 + 4 * k; len = t8;  }
    else if (i < 30)  { src = r3row; int k = i - 20;  gb = v0 - 4 + 4 * k;     len = t16; }
    else if (i < 40)  { src = i3row; int k = i - 30;  gb = v0 - 4 + 4 * k;     len = t16; }
    else if (i < 58)  { src = r2row; int k = i - 40;  gb = u0 - 4 + 4 * k;     len = t8;  }
    else if (i < 76)  { src = i2row; int k = i - 58;  gb = u0 - 4 + 4 * k;     len = t8;  }
    else if (i < 110) { src = r1row; int k = i - 76;  gb = s0 - 4 + 4 * k;     len = t4;  }
    else              { src = i1row; int k = i - 110; gb = s0 - 4 + 4 * k;     len = t4;  }
}

__global__ void __launch_bounds__(FBLOCK) final4_async(
    const float* __restrict__ x4,                                 // T/8 per row
    const float* __restrict__ r3, const float* __restrict__ i3,   // T/16 per row
    const float* __restrict__ r2, const float* __restrict__ i2,   // T/8 per row
    const float* __restrict__ r1, const float* __restrict__ i1,   // T/4 per row
    const float* __restrict__ r0, const float* __restrict__ i0,   // T/2 per row
    float* __restrict__ out,                                      // T per row
    const float* __restrict__ g0a, const float* __restrict__ g0b,
    const float* __restrict__ g1a, const float* __restrict__ g1b,
    const float* __restrict__ g0o, const float* __restrict__ g1o,
    int T_)
{
    const float S2 = 1.4142135623730951f;
    __shared__ __align__(16) float W[W_TOT];

    int row = blockIdx.y, tid = threadIdx.x, bx = blockIdx.x;
    int t2 = T_ >> 1, t4 = T_ >> 2, t8 = T_ >> 3, t16 = T_ >> 4;
    // FT=512: per tile 128 x1-quads owned; s0/u0/v0/h0 in units of each level.
    int s0 = bx << 7, u0 = bx << 6, v0 = bx << 5, h0 = bx << 8;
    const float* x4row = x4 + (size_t)row * t8;
    const float* r3row = r3 + (size_t)row * t16;
    const float* i3row = i3 + (size_t)row * t16;
    const float* r2row = r2 + (size_t)row * t8;
    const float* i2row = i2 + (size_t)row * t8;
    const float* r1row = r1 + (size_t)row * t4;
    const float* i1row = i1 + (size_t)row * t4;
    const float* r0row = r0 + (size_t)row * t2;
    const float* i0row = i0 + (size_t)row * t2;
    bool bnd = (bx == 0) || (bx == (int)gridDim.x - 1);

    // ---- stage: 144 float4 slots, direct HBM -> LDS (wave-linear dest) ----
    if (!bnd) {
        {
            const float* src; int gb, len;
            slot_map(tid, v0, u0, s0, t4, t8, t16,
                     x4row, r3row, i3row, r2row, i2row, r1row, i1row, src, gb, len);
            __builtin_amdgcn_global_load_lds(AS1C(src + gb), AS3(W + 4 * tid), 16, 0, 0);
        }
        if (tid < NSLOT - FBLOCK) {
            const float* src; int gb, len;
            slot_map(tid + FBLOCK, v0, u0, s0, t4, t8, t16,
                     x4row, r3row, i3row, r2row, i2row, r1row, i1row, src, gb, len);
            __builtin_amdgcn_global_load_lds(AS1C(src + gb), AS3(W + 4 * (tid + FBLOCK)), 16, 0, 0);
        }
    } else {
#pragma unroll
        for (int it = 0; it < 2; ++it) {
            int i = tid + FBLOCK * it;
            if (i < NSLOT) {
                const float* src; int gb, len;
                slot_map(i, v0, u0, s0, t4, t8, t16,
                         x4row, r3row, i3row, r2row, i2row, r1row, i1row, src, gb, len);
                float4 v;
                v.x = ldz(src, gb, len);     v.y = ldz(src, gb + 1, len);
                v.z = ldz(src, gb + 2, len); v.w = ldz(src, gb + 3, len);
                *reinterpret_cast<float4*>(W + 4 * i) = v;
            }
        }
    }
    BAR_FULL();   // staged LDS data visible; nothing else in flight yet

    // ---- epilogue loads issued NOW: stay in flight under phases A..C ----
    float rA[4], iA[4];
    {
        int u0e = h0 + 2 * tid - 1;
        if (!bnd) {
            float4 va = *reinterpret_cast<const float4*>(r0row + u0e);
            float4 vb = *reinterpret_cast<const float4*>(i0row + u0e);
            rA[0] = va.x; rA[1] = va.y; rA[2] = va.z; rA[3] = va.w;
            iA[0] = vb.x; iA[1] = vb.y; iA[2] = vb.z; iA[3] = vb.w;
        } else {
#pragma unroll
            for (int e = 0; e < 4; ++e) {
                rA[e] = ldz(r0row, u0e + e, t2);
                iA[e] = ldz(i0row, u0e + e, t2);
            }
        }
    }

    QFiltP f = load_qfiltp(g0a, g0b, g1a, g1b);
    float g0r[7], g1r[5];
#pragma unroll
    for (int j = 0; j < 7; ++j) g0r[j] = g0o[j];
#pragma unroll
    for (int j = 0; j < 5; ++j) g1r[j] = S2 * g1o[j];

    // ---- phase A: 36 x3-quads. quad v = v0-2+k. ----
    if (tid < 36) {
        int k = tid;
        float4 q = quad_p(W, O_X4 + 2 * k, O_R3 + k, 40, f);
        if (bnd) {
            int v = v0 - 2 + k;
            if (v < 0 || v >= t16) q = make_float4(0.f, 0.f, 0.f, 0.f);
        }
        *reinterpret_cast<float4*>(W + O_X3 + 4 * k) = q;
    }
    BAR_LGKM();

    // ---- phase B: 68 x2-quads. quad u = u0-2+k. ----
    if (tid < 68) {
        int k = tid;
        float4 q = quad_p(W, O_X3 + 2 * k, O_R2 + k, 72, f);
        if (bnd) {
            int u = u0 - 2 + k;
            if (u < 0 || u >= t8) q = make_float4(0.f, 0.f, 0.f, 0.f);
        }
        *reinterpret_cast<float4*>(W + O_X2 + 4 * k) = q;
    }
    BAR_LGKM();

    // ---- phase C: 130 x1-quads. quad s = s0-1+l. ----
    float4 myq;
    {
        int l = tid;
        float4 q = quad_p(W, O_X2 + 2 * l + 2, O_R1 + l + 1, 136, f);
        if (bnd) {
            int s = s0 - 1 + l;
            if (s < 0 || s >= t4) q = make_float4(0.f, 0.f, 0.f, 0.f);
        }
        myq = q;
        *reinterpret_cast<float4*>(W + O_X1 + 4 * l) = q;
        if (tid < 2) {
            int l2 = FBLOCK + tid;
            q = quad_p(W, O_X2 + 2 * l2 + 2, O_R1 + l2 + 1, 136, f);
            if (bnd) {
                int s = s0 - 1 + l2;
                if (s < 0 || s >= t4) q = make_float4(0.f, 0.f, 0.f, 0.f);
            }
            *reinterpret_cast<float4*>(W + O_X1 + 4 * l2) = q;
        }
    }
    BAR_LGKM();

    // ---- phase D: epilogue. w[d] = x1[n0-4+4*tid+d]; own quad in regs. ----
    float w[12];
    *reinterpret_cast<float4*>(&w[0]) = myq;
    *reinterpret_cast<float4*>(&w[4]) = *reinterpret_cast<const float4*>(W + O_X1 + 4 * (tid + 1));
    *reinterpret_cast<float4*>(&w[8]) = *reinterpret_cast<const float4*>(W + O_X1 + 4 * (tid + 2));

    float o[4];
#pragma unroll
    for (int p = 0; p < 4; ++p) {
        float acc = 0.f;
#pragma unroll
        for (int j = 0; j < 7; ++j)          // x1[n+3-j] -> w[p+7-j]
            acc = fmaf(g0r[j], w[p + 7 - j], acc);
#pragma unroll
        for (int j = 0; j < 5; ++j) {        // hi0[n+2-j] -> e = p+4-j
            int e = p + 4 - j;
            float v = (e & 1) ? iA[e >> 1] : rA[e >> 1];
            acc = fmaf(g1r[j], v, acc);
        }
        o[p] = acc;
    }
    reinterpret_cast<float4*>(out + (size_t)row * T_)[s0 + tid] =
        make_float4(o[0], o[1], o[2], o[3]);
}

extern "C" void kernel_launch(void* const* d_in, const int* in_sizes, int n_in,
                              void* d_out, int out_size, void* d_ws, size_t ws_size,
                              hipStream_t stream)
{
    const float* yl = (const float*)d_in[0];
    const float* yhr[8]; const float* yhi[8];
    for (int j = 0; j < 8; ++j) {
        yhr[j] = (const float*)d_in[1 + 2 * j];
        yhi[j] = (const float*)d_in[2 + 2 * j];
    }
    const float* g0o = (const float*)d_in[17];
    const float* g1o = (const float*)d_in[18];
    const float* g0a = (const float*)d_in[19];
    const float* g0b = (const float*)d_in[20];
    const float* g1a = (const float*)d_in[21];
    const float* g1b = (const float*)d_in[22];

    const int BC = 32 * 4;
    const int T_ = 262144;

    // Scratch: final reads x4 while writing the FULL d_out, so x4/x6 live in ws.
    float* x4buf = (float*)d_ws;
    float* x6buf = (float*)((char*)d_ws + ((size_t)32 << 20));

    // K76: yl + yh7 + yh6 -> x6 (L = 8192)
    {
        dim3 grid(8192 / 1024, BC);
        pair_lvl<<<grid, PBLOCK, 0, stream>>>(
            yl, yhr[7], yhi[7], yhr[6], yhi[6], x6buf,
            g0a, g0b, g1a, g1b, 8192);
    }
    // K54: x6 + yh5 + yh4 -> x4 (L = 32768)
    {
        dim3 grid(32768 / 1024, BC);
        pair_lvl<<<grid, PBLOCK, 0, stream>>>(
            x6buf, yhr[5], yhi[5], yhr[4], yhi[4], x4buf,
            g0a, g0b, g1a, g1b, 32768);
    }
    // final4_async: x4 + yh3..yh0 -> out. FT=512, 128-thread (2-wave) blocks.
    dim3 grid(T_ / FT, BC);
    final4_async<<<grid, FBLOCK, 0, stream>>>(
        x4buf, yhr[3], yhi[3], yhr[2], yhi[2], yhr[1], yhi[1],
        yhr[0], yhi[0], (float*)d_out,
        g0a, g0b, g1a, g1b, g0o, g1o, T_);
}